// Round 1
// baseline (24346.698 us; speedup 1.0000x reference)
//
#include <hip/hip_runtime.h>

// GRU: B=32, T=2048, I=H=512. Persistent 32-workgroup kernel.
// wg g owns h-columns [g*16, g*16+16). Weight slabs (48 rows each of W_hh and
// W_ih, bf16) live in VGPRs as MFMA A-fragments. h is exchanged per step
// through d_out (fp32) with agent-scope (LLC-coherent) atomics + flags in ws.

#define T_SEQ 2048
#define BATCH 32
#define ISZ 512
#define HSZ 512
#define NG 32      // workgroups
#define CW 16      // h-columns per wg
#define KP 520     // padded LDS row (bf16 elems): stride 1040 B, +4 banks/row

typedef short bf16x8 __attribute__((ext_vector_type(8)));
typedef float f32x4 __attribute__((ext_vector_type(4)));

__device__ __forceinline__ unsigned short f2bf(float f) {
  unsigned int u = __float_as_uint(f);
  unsigned int r = u + 0x7FFFu + ((u >> 16) & 1u);  // RTNE
  return (unsigned short)(r >> 16);
}

// Stage 32 rows x 512 f32 -> bf16 LDS [b][k]. Plain cached loads (read-only src).
__device__ __forceinline__ void stage_plain(const float* base, long rowStride,
                                            unsigned short (*Bst)[KP], int tid) {
  if (tid < 256) {
    const int b = tid >> 3, part = tid & 7;
    const float* src = base + (long)b * rowStride;
#pragma unroll
    for (int i = 0; i < 16; ++i) {
      const int c16 = i * 8 + part;  // 16B chunk id, 0..127
      const float4 f = *(const float4*)(src + c16 * 4);
      ushort4 u;
      u.x = f2bf(f.x); u.y = f2bf(f.y); u.z = f2bf(f.z); u.w = f2bf(f.w);
      *(ushort4*)(&Bst[b][c16 * 4]) = u;
    }
  }
}

// Same, but via agent-scope atomic loads (coherent across XCDs; bypasses
// stale L1/L2). Issues all 32 loads before converting so they pipeline.
__device__ __forceinline__ void stage_remote(const float* base, long rowStride,
                                             unsigned short (*Bst)[KP], int tid) {
  if (tid < 256) {
    const int b = tid >> 3, part = tid & 7;
    const unsigned long long* src =
        (const unsigned long long*)(base + (long)b * rowStride);
    unsigned long long tmp[32];
#pragma unroll
    for (int i = 0; i < 32; ++i)
      tmp[i] = __hip_atomic_load((unsigned long long*)&src[(long)i * 8 + part],
                                 __ATOMIC_RELAXED, __HIP_MEMORY_SCOPE_AGENT);
#pragma unroll
    for (int i = 0; i < 32; ++i) {
      const int c = i * 8 + part;  // u64 chunk, 0..255
      const unsigned int lo = (unsigned int)tmp[i];
      const unsigned int hi = (unsigned int)(tmp[i] >> 32);
      const unsigned int packed = (unsigned int)f2bf(__uint_as_float(lo)) |
                                  ((unsigned int)f2bf(__uint_as_float(hi)) << 16);
      *(unsigned int*)(&Bst[b][c * 2]) = packed;
    }
  }
}

// 16x16 output tile: A-slab (16 K-frags in regs) x B (h/input staged in LDS).
__device__ __forceinline__ f32x4 mfma_slab(const bf16x8* a,
                                           unsigned short (*Bst)[KP],
                                           int bt, int n16, int quad) {
  f32x4 acc = {0.f, 0.f, 0.f, 0.f};
#pragma unroll
  for (int kk = 0; kk < 16; ++kk) {
    const bf16x8 bf = *(const bf16x8*)(&Bst[bt * 16 + n16][kk * 32 + quad * 8]);
    acc = __builtin_amdgcn_mfma_f32_16x16x32_bf16(a[kk], bf, acc, 0, 0, 0);
  }
  return acc;
}

__global__ __launch_bounds__(384, 2) void gru_persistent(
    const float* __restrict__ in, const float* __restrict__ h0,
    const float* __restrict__ wih, const float* __restrict__ whh,
    const float* __restrict__ bihp, const float* __restrict__ bhhp,
    float* __restrict__ out, unsigned int* __restrict__ flags) {
  __shared__ unsigned short Bstage[BATCH][KP];  // B-operand stage (h or input)
  __shared__ float xg[3][CW][33];               // input gates for current t
  __shared__ float hg[3][CW][33];               // hidden gates
  __shared__ float own_h[CW][BATCH];            // fp32 carried state (own slice)
  __shared__ float bih_l[48], bhh_l[48];

  const int tid = threadIdx.x;
  const int g = blockIdx.x;
  const int c0 = g * CW;
  const int lane = tid & 63, wid = tid >> 6;
  const int n16 = lane & 15, quad = lane >> 4;
  const int rt = wid % 3, bt = wid / 3;  // gate index, batch tile

  // ---- prologue: biases for this wg's 48 rows ----
  if (tid < 48) bih_l[tid] = bihp[(tid >> 4) * HSZ + c0 + (tid & 15)];
  else if (tid >= 64 && tid < 112) {
    const int lr = tid - 64;
    bhh_l[lr] = bhhp[(lr >> 4) * HSZ + c0 + (lr & 15)];
  }

  // ---- weight slabs -> registers (MFMA A-frag layout: m=lane&15, k=quad*8+j)
  bf16x8 a_hh[16], a_ih[16];
  {
    const long grow = rt * HSZ + c0 + n16;
    const float* wr_h = whh + grow * HSZ;
    const float* wr_i = wih + grow * ISZ;
#pragma unroll
    for (int kk = 0; kk < 16; ++kk) {
      const int k0 = kk * 32 + quad * 8;
      float4 f0 = *(const float4*)(wr_h + k0);
      float4 f1 = *(const float4*)(wr_h + k0 + 4);
      bf16x8 v;
      v[0] = (short)f2bf(f0.x); v[1] = (short)f2bf(f0.y);
      v[2] = (short)f2bf(f0.z); v[3] = (short)f2bf(f0.w);
      v[4] = (short)f2bf(f1.x); v[5] = (short)f2bf(f1.y);
      v[6] = (short)f2bf(f1.z); v[7] = (short)f2bf(f1.w);
      a_hh[kk] = v;
      f0 = *(const float4*)(wr_i + k0);
      f1 = *(const float4*)(wr_i + k0 + 4);
      v[0] = (short)f2bf(f0.x); v[1] = (short)f2bf(f0.y);
      v[2] = (short)f2bf(f0.z); v[3] = (short)f2bf(f0.w);
      v[4] = (short)f2bf(f1.x); v[5] = (short)f2bf(f1.y);
      v[6] = (short)f2bf(f1.z); v[7] = (short)f2bf(f1.w);
      a_ih[kk] = v;
    }
  }

  // ---- xg for t=0 ----
  stage_plain(in, (long)T_SEQ * ISZ, Bstage, tid);
  __syncthreads();
  {
    f32x4 acc = mfma_slab(a_ih, Bstage, bt, n16, quad);
#pragma unroll
    for (int r = 0; r < 4; ++r)
      xg[rt][quad * 4 + r][bt * 16 + n16] = acc[r] + bih_l[rt * 16 + quad * 4 + r];
  }
  __syncthreads();

  for (int t = 0; t < T_SEQ; ++t) {
    // ---- Phase A: obtain h(t-1) into Bstage ----
    if (t == 0) {
      stage_plain(h0, HSZ, Bstage, tid);
      if (tid < 256) {
        const int b = tid & 31, cb = (tid >> 5) << 1;
        own_h[cb][b] = h0[b * HSZ + c0 + cb];
        own_h[cb + 1][b] = h0[b * HSZ + c0 + cb + 1];
      }
    } else {
      if (wid == 0) {
        const unsigned int want = 0x47520000u | (unsigned int)t;
        for (;;) {
          unsigned int v = want;
          if (lane < 32)
            v = __hip_atomic_load(&flags[(t - 1) * NG + lane], __ATOMIC_RELAXED,
                                  __HIP_MEMORY_SCOPE_AGENT);
          if (__all(v == want)) break;
          __builtin_amdgcn_s_sleep(2);
        }
      }
      __syncthreads();
      asm volatile("" ::: "memory");
      stage_remote(out + (long)(t - 1) * HSZ, (long)T_SEQ * HSZ, Bstage, tid);
    }
    __syncthreads();

    // ---- Phase B: hg = W_hh(slab) @ h ----
    {
      f32x4 acc = mfma_slab(a_hh, Bstage, bt, n16, quad);
#pragma unroll
      for (int r = 0; r < 4; ++r)
        hg[rt][quad * 4 + r][bt * 16 + n16] = acc[r];
    }
    __syncthreads();

    // ---- Phase C: gates + store h slice ----
    if (tid < 256) {
      const int b = tid & 31, cb = (tid >> 5) << 1;
      float h2[2];
#pragma unroll
      for (int j = 0; j < 2; ++j) {
        const int col = cb + j;
        const float xr = xg[0][col][b], xz = xg[1][col][b], xn = xg[2][col][b];
        const float hr = hg[0][col][b] + bhh_l[col];
        const float hz = hg[1][col][b] + bhh_l[16 + col];
        const float hn = hg[2][col][b] + bhh_l[32 + col];
        const float r = 1.f / (1.f + __expf(-(xr + hr)));
        const float z = 1.f / (1.f + __expf(-(xz + hz)));
        const float aa = xn + r * hn;
        const float e = __expf(-2.f * fabsf(aa));
        float th = (1.f - e) / (1.f + e);
        th = copysignf(th, aa);
        const float hp = own_h[col][b];
        const float hnew = (1.f - z) * th + z * hp;
        own_h[col][b] = hnew;
        h2[j] = hnew;
      }
      const unsigned long long val =
          ((unsigned long long)__float_as_uint(h2[1]) << 32) |
          (unsigned long long)__float_as_uint(h2[0]);
      __hip_atomic_store(
          (unsigned long long*)(out + (long)b * T_SEQ * HSZ + (long)t * HSZ + c0 + cb),
          val, __ATOMIC_RELAXED, __HIP_MEMORY_SCOPE_AGENT);
    }
    asm volatile("s_waitcnt vmcnt(0)" ::: "memory");  // h slice visible at LLC
    __syncthreads();
    if (tid == 0)
      __hip_atomic_store(&flags[t * NG + g], 0x47520000u | (unsigned int)(t + 1),
                         __ATOMIC_RELAXED, __HIP_MEMORY_SCOPE_AGENT);

    // ---- Phase D: xg for t+1 (input side, independent of recurrence) ----
    if (t + 1 < T_SEQ) {
      stage_plain(in + (long)(t + 1) * ISZ, (long)T_SEQ * ISZ, Bstage, tid);
      __syncthreads();
      f32x4 acc = mfma_slab(a_ih, Bstage, bt, n16, quad);
#pragma unroll
      for (int r = 0; r < 4; ++r)
        xg[rt][quad * 4 + r][bt * 16 + n16] =
            acc[r] + bih_l[rt * 16 + quad * 4 + r];
      __syncthreads();
    }
  }
}

extern "C" void kernel_launch(void* const* d_in, const int* in_sizes, int n_in,
                              void* d_out, int out_size, void* d_ws, size_t ws_size,
                              hipStream_t stream) {
  const float* in  = (const float*)d_in[0];
  const float* h0  = (const float*)d_in[1];
  const float* wih = (const float*)d_in[2];
  const float* whh = (const float*)d_in[3];
  const float* bih = (const float*)d_in[4];
  const float* bhh = (const float*)d_in[5];
  float* out = (float*)d_out;
  unsigned int* flags = (unsigned int*)d_ws;  // T*NG u32 = 256 KB

  gru_persistent<<<dim3(NG), dim3(384), 0, stream>>>(in, h0, wih, whh, bih, bhh,
                                                     out, flags);
}